// Round 7
// baseline (310.295 us; speedup 1.0000x reference)
//
#include <hip/hip_runtime.h>
#include <math.h>

#define NE  8
#define HID 256

typedef __attribute__((ext_vector_type(8)))  short short8;
typedef __attribute__((ext_vector_type(16))) float f32x16;

static __device__ __forceinline__ unsigned short f2bf(float f) {
    unsigned int u = __float_as_uint(f);
    return (unsigned short)((u + 0x7FFFu + ((u >> 16) & 1u)) >> 16);
}

static __device__ __forceinline__ short8 pack8(float4 a, float4 b) {
    short8 r;
    r[0] = (short)f2bf(a.x); r[1] = (short)f2bf(a.y);
    r[2] = (short)f2bf(a.z); r[3] = (short)f2bf(a.w);
    r[4] = (short)f2bf(b.x); r[5] = (short)f2bf(b.y);
    r[6] = (short)f2bf(b.z); r[7] = (short)f2bf(b.w);
    return r;
}

// ---------------------------------------------------------------------------
// Kernel 1 (blocks 0..1023): W1 [E][128][256] -> bf16 frag-linear.
//   frag (e, hrt<8, kt<8): [lane][j] = W1[e][kt*16+(lane>>5)*8+j][hrt*32+(lane&31)]
// Block 1024: pk table [e][hrt][q][g][8] f32: j<4 -> b1[h], j>=4 -> W2[h].
// ---------------------------------------------------------------------------
__global__ void prep_w1(const float* __restrict__ W1, const float* __restrict__ b1,
                        const float* __restrict__ W2,
                        unsigned short* __restrict__ wfr, float* __restrict__ pk) {
    if (blockIdx.x < 1024) {
        int f = blockIdx.x * 256 + threadIdx.x;     // 262144 total
        int j   = f & 7;
        int l   = (f >> 3) & 63;
        int kt  = (f >> 9) & 7;
        int hrt = (f >> 12) & 7;
        int e   = f >> 15;
        int k = kt * 16 + ((l >> 5) * 8) + j;
        int h = hrt * 32 + (l & 31);
        wfr[f] = f2bf(W1[((size_t)e * 128 + k) * HID + h]);
    } else {
        for (int i = threadIdx.x; i < 4096; i += 256) {
            int j   = i & 7;
            int g   = (i >> 3) & 1;
            int q   = (i >> 4) & 3;
            int hrt = (i >> 6) & 7;
            int e   = i >> 9;
            int h = hrt * 32 + q * 8 + g * 4 + (j & 3);
            pk[i] = (j < 4) ? b1[e * HID + h] : W2[e * HID + h];
        }
    }
}

// ---------------------------------------------------------------------------
// Kernel 2: gating softmax + experts_used + partials; also zeroes pred
// (pred must be exactly 0 so the two expert-group atomicAdds are
//  bit-deterministic: fl(fl(0+a)+b) == fl(fl(0+b)+a)).
// ---------------------------------------------------------------------------
__global__ void gates_kernel(const float* __restrict__ cp,
                             float* __restrict__ gates_out,
                             float* __restrict__ used_out,
                             float* __restrict__ part,
                             float* __restrict__ pred_zero) {
    __shared__ float wp_[4][16];
    int tid = threadIdx.x;
    int b = blockIdx.x * 256 + tid;

    pred_zero[b] = 0.f;

    float g[8];
    {
        const float4* c4 = (const float4*)(cp + (size_t)b * NE);
        float4 a0 = c4[0], a1 = c4[1];
        g[0]=a0.x; g[1]=a0.y; g[2]=a0.z; g[3]=a0.w;
        g[4]=a1.x; g[5]=a1.y; g[6]=a1.z; g[7]=a1.w;
    }
    float m = g[0];
    #pragma unroll
    for (int i = 1; i < 8; ++i) m = fmaxf(m, g[i]);
    float s = 0.f;
    #pragma unroll
    for (int i = 0; i < 8; ++i) { g[i] = __expf(g[i] - m); s += g[i]; }
    float inv = 1.f / s;
    #pragma unroll
    for (int i = 0; i < 8; ++i) g[i] *= inv;

    {
        float4 o0 = make_float4(g[0], g[1], g[2], g[3]);
        float4 o1 = make_float4(g[4], g[5], g[6], g[7]);
        float4* g4 = (float4*)(gates_out + (size_t)b * NE);
        g4[0] = o0; g4[1] = o1;
    }
    float v[16];
    float used = 0.f;
    #pragma unroll
    for (int i = 0; i < 8; ++i) {
        float a = (g[i] > 0.01f) ? 1.f : 0.f;
        used += a;
        v[i] = g[i];
        v[8 + i] = a;
    }
    used_out[b] = used;

    #pragma unroll
    for (int d = 32; d >= 1; d >>= 1)
        #pragma unroll
        for (int i = 0; i < 16; ++i)
            v[i] += __shfl_down(v[i], d, 64);
    int lane = tid & 63, wid = tid >> 6;
    if (lane == 0)
        #pragma unroll
        for (int i = 0; i < 16; ++i) wp_[wid][i] = v[i];
    __syncthreads();
    if (tid < 16)
        part[(size_t)blockIdx.x * 16 + tid] =
            wp_[0][tid] + wp_[1][tid] + wp_[2][tid] + wp_[3][tid];
}

__global__ void reduce_kernel(const float* __restrict__ part,
                              float* __restrict__ inf_out,
                              float* __restrict__ cnt_out) {
    int t = threadIdx.x;
    if (t >= 16) return;
    float s = 0.f;
    for (int i = 0; i < 512; ++i) s += part[(size_t)i * 16 + t];
    if (t < 8) inf_out[t] = s;
    else       cnt_out[t - 8] = s;
}

// ---------------------------------------------------------------------------
// Kernel 4: main MoE. 512 blocks x 256 thr (4 waves):
//   grp = blockIdx>>8 (4 experts), tb = blockIdx&255 (512 tokens).
// Wave = 128 tokens (tt=4): each w1 ds_read feeds 4 MFMAs (2x round 6).
// VGPR ~240 (<=256 tier -> 8 waves/CU) + 72KB LDS -> 2 blocks/CU,
// unsynchronized -> one block's MFMA hides the other's barriers/epilogue.
// NOTE: launch_bounds(512,4) caused spill catastrophe (round 5); (256,2)
// caps at exactly 256 VGPR which the live set fits.
// ---------------------------------------------------------------------------
__global__ __launch_bounds__(256, 2)
void moe_main(const float* __restrict__ x,
              const unsigned short* __restrict__ wfr,
              const float* __restrict__ pk,
              const float* __restrict__ b2,
              const float* __restrict__ gates,
              float* __restrict__ pred_out) {
    __shared__ unsigned short W1s[8 * 8 * 64 * 8];   // 64 KB (hrt-major)
    __shared__ float pks[2048];                      // 8 KB (group slice)

    const int tid  = threadIdx.x;
    const int lane = tid & 63;
    const int wid  = tid >> 6;          // 0..3
    const int g    = lane >> 5;
    const int col  = lane & 31;
    const int grp  = blockIdx.x >> 8;   // expert group: e in [grp*4, grp*4+4)
    const int tb   = blockIdx.x & 255;
    const int tw   = tb * 512 + wid * 128;           // wave token base
    const int e0   = grp * 4;

    // ---- stage both halves of expert e0 (64 KB = 256 thr x 8 x 1KB x 2)
    {
        const char* src = (const char*)wfr + (size_t)e0 * 65536 + wid * 8192 + lane * 16;
        char* dst = (char*)&W1s[0] + wid * 8192;
        #pragma unroll
        for (int i = 0; i < 8; ++i) {
            __builtin_amdgcn_global_load_lds(
                (const __attribute__((address_space(1))) unsigned int*)(src + i * 1024),
                (__attribute__((address_space(3))) unsigned int*)(dst + i * 1024),
                16, 0, 0);
            __builtin_amdgcn_global_load_lds(
                (const __attribute__((address_space(1))) unsigned int*)(src + 32768 + i * 1024),
                (__attribute__((address_space(3))) unsigned int*)(dst + 32768 + i * 1024),
                16, 0, 0);
        }
    }
    // ---- pk group slice -> LDS (512 float4)
    ((float4*)pks)[tid]       = ((const float4*)(pk + grp * 2048))[tid];
    ((float4*)pks)[tid + 256] = ((const float4*)(pk + grp * 2048))[tid + 256];

    // ---- x fragments -> registers: frag (tt<4, kt<8): token=tw+tt*32+col,
    //      k = kt*16 + g*8 + j    (128 VGPR, pinned for whole kernel)
    short8 xf[4][8];
    #pragma unroll
    for (int tt = 0; tt < 4; ++tt) {
        const float* xr = x + ((size_t)(tw + tt * 32 + col)) * 128 + g * 8;
        #pragma unroll
        for (int kt = 0; kt < 8; ++kt) {
            float4 a = *(const float4*)(xr + kt * 16);
            float4 b = *(const float4*)(xr + kt * 16 + 4);
            xf[tt][kt] = pack8(a, b);
        }
    }

    float pred[4] = {0.f, 0.f, 0.f, 0.f};
    __syncthreads();   // drains: stage(e0), pks, x loads

    for (int ee = 0; ee < 4; ++ee) {
        const int e = e0 + ee;
        float yacc[4] = {0.f, 0.f, 0.f, 0.f};

        // ---------- half A: hrt 0..3 ----------
        for (int hrt = 0; hrt < 4; ++hrt) {
            f32x16 acc[4];
            #pragma unroll
            for (int tt = 0; tt < 4; ++tt) acc[tt] = (f32x16)0.0f;
            #pragma unroll
            for (int kt = 0; kt < 8; ++kt) {
                short8 w = *(const short8*)&W1s[((hrt * 8 + kt) * 64 + lane) * 8];
                #pragma unroll
                for (int tt = 0; tt < 4; ++tt)
                    acc[tt] = __builtin_amdgcn_mfma_f32_32x32x16_bf16(w, xf[tt][kt], acc[tt], 0, 0, 0);
            }
            #pragma unroll
            for (int q = 0; q < 4; ++q) {
                int base = (((ee * 8 + hrt) * 4 + q) * 2 + g) * 8;
                float4 b1q = *(const float4*)&pks[base];
                float4 w2q = *(const float4*)&pks[base + 4];
                #pragma unroll
                for (int tt = 0; tt < 4; ++tt) {
                    yacc[tt] = fmaf(fmaxf(acc[tt][q * 4 + 0] + b1q.x, 0.f), w2q.x, yacc[tt]);
                    yacc[tt] = fmaf(fmaxf(acc[tt][q * 4 + 1] + b1q.y, 0.f), w2q.y, yacc[tt]);
                    yacc[tt] = fmaf(fmaxf(acc[tt][q * 4 + 2] + b1q.z, 0.f), w2q.z, yacc[tt]);
                    yacc[tt] = fmaf(fmaxf(acc[tt][q * 4 + 3] + b1q.w, 0.f), w2q.w, yacc[tt]);
                }
            }
        }

        __syncthreads();   // all reads of half A done (prev stage long drained)
        if (ee < 3) {      // stage half A <- expert e+1 (overlaps half-B compute)
            const char* src = (const char*)wfr + (size_t)(e + 1) * 65536 + wid * 8192 + lane * 16;
            char* dst = (char*)&W1s[0] + wid * 8192;
            #pragma unroll
            for (int i = 0; i < 8; ++i)
                __builtin_amdgcn_global_load_lds(
                    (const __attribute__((address_space(1))) unsigned int*)(src + i * 1024),
                    (__attribute__((address_space(3))) unsigned int*)(dst + i * 1024),
                    16, 0, 0);
        }

        // ---------- half B: hrt 4..7 ----------
        for (int hrt = 4; hrt < 8; ++hrt) {
            f32x16 acc[4];
            #pragma unroll
            for (int tt = 0; tt < 4; ++tt) acc[tt] = (f32x16)0.0f;
            #pragma unroll
            for (int kt = 0; kt < 8; ++kt) {
                short8 w = *(const short8*)&W1s[((hrt * 8 + kt) * 64 + lane) * 8];
                #pragma unroll
                for (int tt = 0; tt < 4; ++tt)
                    acc[tt] = __builtin_amdgcn_mfma_f32_32x32x16_bf16(w, xf[tt][kt], acc[tt], 0, 0, 0);
            }
            #pragma unroll
            for (int q = 0; q < 4; ++q) {
                int base = (((ee * 8 + hrt) * 4 + q) * 2 + g) * 8;
                float4 b1q = *(const float4*)&pks[base];
                float4 w2q = *(const float4*)&pks[base + 4];
                #pragma unroll
                for (int tt = 0; tt < 4; ++tt) {
                    yacc[tt] = fmaf(fmaxf(acc[tt][q * 4 + 0] + b1q.x, 0.f), w2q.x, yacc[tt]);
                    yacc[tt] = fmaf(fmaxf(acc[tt][q * 4 + 1] + b1q.y, 0.f), w2q.y, yacc[tt]);
                    yacc[tt] = fmaf(fmaxf(acc[tt][q * 4 + 2] + b1q.z, 0.f), w2q.z, yacc[tt]);
                    yacc[tt] = fmaf(fmaxf(acc[tt][q * 4 + 3] + b1q.w, 0.f), w2q.w, yacc[tt]);
                }
            }
        }

        // sigmoid + gate-weight into per-group partial
        float bb = b2[e];
        #pragma unroll
        for (int tt = 0; tt < 4; ++tt) {
            float s = yacc[tt] + __shfl_xor(yacc[tt], 32, 64) + bb;
            float yv = 1.f / (1.f + __expf(-s));
            float gt = gates[(size_t)(tw + tt * 32 + col) * NE + e];
            pred[tt] = fmaf(gt, yv, pred[tt]);
        }

        __syncthreads();   // half-B reads done; drains half-A stage of e+1
        if (ee < 3) {      // stage half B <- expert e+1 (overlaps next half-A)
            const char* src = (const char*)wfr + (size_t)(e + 1) * 65536 + 32768 + wid * 8192 + lane * 16;
            char* dst = (char*)&W1s[0] + 32768 + wid * 8192;
            #pragma unroll
            for (int i = 0; i < 8; ++i)
                __builtin_amdgcn_global_load_lds(
                    (const __attribute__((address_space(1))) unsigned int*)(src + i * 1024),
                    (__attribute__((address_space(3))) unsigned int*)(dst + i * 1024),
                    16, 0, 0);
        }
    }

    // combine the two expert-group partials (exactly 2 addends on zeroed slot
    // -> bit-deterministic)
    #pragma unroll
    for (int tt = 0; tt < 4; ++tt)
        if (lane < 32) atomicAdd(&pred_out[tw + tt * 32 + col], pred[tt]);
}

// ---------------------------------------------------------------------------
extern "C" void kernel_launch(void* const* d_in, const int* in_sizes, int n_in,
                              void* d_out, int out_size, void* d_ws, size_t ws_size,
                              hipStream_t stream) {
    (void)in_sizes; (void)n_in; (void)out_size; (void)ws_size;
    const float* x  = (const float*)d_in[0];
    const float* cp = (const float*)d_in[1];
    const float* W1 = (const float*)d_in[2];
    const float* b1 = (const float*)d_in[3];
    const float* W2 = (const float*)d_in[4];
    const float* b2 = (const float*)d_in[5];

    float* out   = (float*)d_out;
    float* pred  = out;                       // [131072]
    float* gates = out + 131072;              // [131072*8]
    float* used  = out + 1179648;             // [131072]
    float* inf   = out + 1310720;             // [8]
    float* cnt   = out + 1310728;             // [8]

    unsigned short* wfrag = (unsigned short*)d_ws;           // 512 KB frag W1
    float* pk   = (float*)((char*)d_ws + 524288);            // 16 KB b1/w2 table
    float* part = (float*)((char*)d_ws + 540672);            // 32 KB partials

    prep_w1<<<dim3(1025), dim3(256), 0, stream>>>(W1, b1, W2, wfrag, pk);
    gates_kernel<<<dim3(512), dim3(256), 0, stream>>>(cp, gates, used, part, pred);
    reduce_kernel<<<dim3(1), dim3(64), 0, stream>>>(part, inf, cnt);
    moe_main<<<dim3(512), dim3(256), 0, stream>>>(x, wfrag, pk, b2, gates, pred);
}

// Round 8
// 110.205 us; speedup vs baseline: 2.8156x; 2.8156x over previous
//
#include <hip/hip_runtime.h>
#include <math.h>

#define NE  8
#define HID 256

typedef __attribute__((ext_vector_type(8)))  short short8;
typedef __attribute__((ext_vector_type(16))) float f32x16;

static __device__ __forceinline__ unsigned short f2bf(float f) {
    unsigned int u = __float_as_uint(f);
    return (unsigned short)((u + 0x7FFFu + ((u >> 16) & 1u)) >> 16);
}

static __device__ __forceinline__ short8 pack8(float4 a, float4 b) {
    short8 r;
    r[0] = (short)f2bf(a.x); r[1] = (short)f2bf(a.y);
    r[2] = (short)f2bf(a.z); r[3] = (short)f2bf(a.w);
    r[4] = (short)f2bf(b.x); r[5] = (short)f2bf(b.y);
    r[6] = (short)f2bf(b.z); r[7] = (short)f2bf(b.w);
    return r;
}

// ---------------------------------------------------------------------------
// Kernel 1 (blocks 0..1023): W1 [E][128][256] -> bf16 frag-linear.
//   frag (e, hrt<8, kt<8): [lane][j] = W1[e][kt*16+(lane>>5)*8+j][hrt*32+(lane&31)]
// Block 1024: pk table [e][hrt][q][g][8] f32: j<4 -> b1[h], j>=4 -> W2[h].
// ---------------------------------------------------------------------------
__global__ void prep_w1(const float* __restrict__ W1, const float* __restrict__ b1,
                        const float* __restrict__ W2,
                        unsigned short* __restrict__ wfr, float* __restrict__ pk) {
    if (blockIdx.x < 1024) {
        int f = blockIdx.x * 256 + threadIdx.x;     // 262144 total
        int j   = f & 7;
        int l   = (f >> 3) & 63;
        int kt  = (f >> 9) & 7;
        int hrt = (f >> 12) & 7;
        int e   = f >> 15;
        int k = kt * 16 + ((l >> 5) * 8) + j;
        int h = hrt * 32 + (l & 31);
        wfr[f] = f2bf(W1[((size_t)e * 128 + k) * HID + h]);
    } else {
        for (int i = threadIdx.x; i < 4096; i += 256) {
            int j   = i & 7;
            int g   = (i >> 3) & 1;
            int q   = (i >> 4) & 3;
            int hrt = (i >> 6) & 7;
            int e   = i >> 9;
            int h = hrt * 32 + q * 8 + g * 4 + (j & 3);
            pk[i] = (j < 4) ? b1[e * HID + h] : W2[e * HID + h];
        }
    }
}

// ---------------------------------------------------------------------------
// Kernel 2: gating softmax (exact fp32) + experts_used + per-block partials
// ---------------------------------------------------------------------------
__global__ void gates_kernel(const float* __restrict__ cp,
                             float* __restrict__ gates_out,
                             float* __restrict__ used_out,
                             float* __restrict__ part) {
    __shared__ float wp_[4][16];
    int tid = threadIdx.x;
    int b = blockIdx.x * 256 + tid;

    float g[8];
    {
        const float4* c4 = (const float4*)(cp + (size_t)b * NE);
        float4 a0 = c4[0], a1 = c4[1];
        g[0]=a0.x; g[1]=a0.y; g[2]=a0.z; g[3]=a0.w;
        g[4]=a1.x; g[5]=a1.y; g[6]=a1.z; g[7]=a1.w;
    }
    float m = g[0];
    #pragma unroll
    for (int i = 1; i < 8; ++i) m = fmaxf(m, g[i]);
    float s = 0.f;
    #pragma unroll
    for (int i = 0; i < 8; ++i) { g[i] = __expf(g[i] - m); s += g[i]; }
    float inv = 1.f / s;
    #pragma unroll
    for (int i = 0; i < 8; ++i) g[i] *= inv;

    {
        float4 o0 = make_float4(g[0], g[1], g[2], g[3]);
        float4 o1 = make_float4(g[4], g[5], g[6], g[7]);
        float4* g4 = (float4*)(gates_out + (size_t)b * NE);
        g4[0] = o0; g4[1] = o1;
    }
    float v[16];
    float used = 0.f;
    #pragma unroll
    for (int i = 0; i < 8; ++i) {
        float a = (g[i] > 0.01f) ? 1.f : 0.f;
        used += a;
        v[i] = g[i];
        v[8 + i] = a;
    }
    used_out[b] = used;

    #pragma unroll
    for (int d = 32; d >= 1; d >>= 1)
        #pragma unroll
        for (int i = 0; i < 16; ++i)
            v[i] += __shfl_down(v[i], d, 64);
    int lane = tid & 63, wid = tid >> 6;
    if (lane == 0)
        #pragma unroll
        for (int i = 0; i < 16; ++i) wp_[wid][i] = v[i];
    __syncthreads();
    if (tid < 16)
        part[(size_t)blockIdx.x * 16 + tid] =
            wp_[0][tid] + wp_[1][tid] + wp_[2][tid] + wp_[3][tid];
}

__global__ void reduce_kernel(const float* __restrict__ part,
                              float* __restrict__ inf_out,
                              float* __restrict__ cnt_out) {
    int t = threadIdx.x;
    if (t >= 16) return;
    float s = 0.f;
    for (int i = 0; i < 512; ++i) s += part[(size_t)i * 16 + t];
    if (t < 8) inf_out[t] = s;
    else       cnt_out[t - 8] = s;
}

// ---------------------------------------------------------------------------
// Kernel 4: main MoE. 256 blocks x 1024 thr (16 waves = 4 waves/SIMD).
// h-split: wave pair (w, w+8) = same 64 tokens; w computes hrt 0..3,
// w+8 computes hrt 4..7. tt=2 (64 tokens/wave), xf pinned (64 VGPR).
// W1 double-buffered 2x64KB; ONE barrier per expert. Half-B hands its
// y-partial to half-A via double-buffered ybuf; half-A does sigmoid+gate
// +store AFTER the barrier while half-B runs ahead -> waves out-of-phase
// on each SIMD. No atomics (deterministic direct stores).
// Empirical (r2/3/6/7): 2nd block/CU never co-resides -> 1 big block/CU.
// launch_bounds(1024,4) caps VGPR at 128; live set ~116 (r3-proven).
// ---------------------------------------------------------------------------
__global__ __launch_bounds__(1024, 4)
void moe_main(const float* __restrict__ x,
              const unsigned short* __restrict__ wfr,
              const float* __restrict__ pk,
              const float* __restrict__ b2,
              const float* __restrict__ gates,
              float* __restrict__ pred_out) {
    __shared__ unsigned short W1s[2][8 * 8 * 64 * 8];   // 2 x 64 KB
    __shared__ float pks[4096];                         // 16 KB
    __shared__ float ybuf[2][8][2][32];                 // 4 KB (dbuf by e&1)

    const int tid  = threadIdx.x;
    const int lane = tid & 63;
    const int wid  = tid >> 6;          // 0..15
    const int tg   = wid & 7;           // token group (pairs share tg)
    const int hh   = wid >> 3;          // h-half: 0 -> hrt 0..3, 1 -> hrt 4..7
    const int g    = lane >> 5;
    const int col  = lane & 31;
    const int tw   = blockIdx.x * 512 + tg * 64;     // wave token base

    // ---- stage expert 0 into buf 0 (64 KB = 1024 thr x 4 x 16B)
    {
        const char* src = (const char*)wfr + (size_t)tid * 16;
        char* dst = (char*)&W1s[0][0];
        #pragma unroll
        for (int i = 0; i < 4; ++i)
            __builtin_amdgcn_global_load_lds(
                (const __attribute__((address_space(1))) unsigned int*)(src + i * 16384),
                (__attribute__((address_space(3))) unsigned int*)(dst + tid * 16 + i * 16384),
                16, 0, 0);
    }
    // ---- pk table -> LDS (1024 float4 over 1024 threads)
    ((float4*)pks)[tid] = ((const float4*)pk)[tid];

    // ---- x fragments -> registers: frag (tt<2, kt<8): token=tw+tt*32+col,
    //      k = kt*16 + g*8 + j
    short8 xf[2][8];
    #pragma unroll
    for (int tt = 0; tt < 2; ++tt) {
        const float* xr = x + ((size_t)(tw + tt * 32 + col)) * 128 + g * 8;
        #pragma unroll
        for (int kt = 0; kt < 8; ++kt) {
            float4 a = *(const float4*)(xr + kt * 16);
            float4 b = *(const float4*)(xr + kt * 16 + 4);
            xf[tt][kt] = pack8(a, b);
        }
    }

    float pred[2] = {0.f, 0.f};
    int p = 0;
    __syncthreads();   // drains: stage(e0), pks, x loads

    for (int e = 0; e < NE; ++e) {
        if (e < 7) {   // stage next expert into other buffer (drained at barrier)
            const char* src = (const char*)wfr + (size_t)(e + 1) * 65536 + (size_t)tid * 16;
            char* dst = (char*)&W1s[p ^ 1][0];
            #pragma unroll
            for (int i = 0; i < 4; ++i)
                __builtin_amdgcn_global_load_lds(
                    (const __attribute__((address_space(1))) unsigned int*)(src + i * 16384),
                    (__attribute__((address_space(3))) unsigned int*)(dst + tid * 16 + i * 16384),
                    16, 0, 0);
        }

        float yacc[2] = {0.f, 0.f};
        #pragma unroll
        for (int hr = 0; hr < 4; ++hr) {
            const int hrt = hh * 4 + hr;
            f32x16 acc[2];
            acc[0] = (f32x16)0.0f; acc[1] = (f32x16)0.0f;
            #pragma unroll
            for (int kt = 0; kt < 8; ++kt) {
                short8 w = *(const short8*)&W1s[p][((hrt * 8 + kt) * 64 + lane) * 8];
                acc[0] = __builtin_amdgcn_mfma_f32_32x32x16_bf16(w, xf[0][kt], acc[0], 0, 0, 0);
                acc[1] = __builtin_amdgcn_mfma_f32_32x32x16_bf16(w, xf[1][kt], acc[1], 0, 0, 0);
            }
            // yacc += relu(acc + b1) * w2, h = hrt*32 + 8q + 4g + i
            #pragma unroll
            for (int q = 0; q < 4; ++q) {
                int base = (((e * 8 + hrt) * 4 + q) * 2 + g) * 8;
                float4 b1q = *(const float4*)&pks[base];
                float4 w2q = *(const float4*)&pks[base + 4];
                #pragma unroll
                for (int tt = 0; tt < 2; ++tt) {
                    yacc[tt] = fmaf(fmaxf(acc[tt][q * 4 + 0] + b1q.x, 0.f), w2q.x, yacc[tt]);
                    yacc[tt] = fmaf(fmaxf(acc[tt][q * 4 + 1] + b1q.y, 0.f), w2q.y, yacc[tt]);
                    yacc[tt] = fmaf(fmaxf(acc[tt][q * 4 + 2] + b1q.z, 0.f), w2q.z, yacc[tt]);
                    yacc[tt] = fmaf(fmaxf(acc[tt][q * 4 + 3] + b1q.w, 0.f), w2q.w, yacc[tt]);
                }
            }
        }

        // fold lane<->lane+32 (complementary h-rows, same token col)
        #pragma unroll
        for (int tt = 0; tt < 2; ++tt)
            yacc[tt] += __shfl_xor(yacc[tt], 32, 64);

        // half-B publishes its partial for this expert
        if (hh == 1 && lane < 32) {
            ybuf[e & 1][tg][0][col] = yacc[0];
            ybuf[e & 1][tg][1][col] = yacc[1];
        }

        __syncthreads();   // ybuf visible; buf[p] reads done; stage(e+1) drained

        // half-A combines, sigmoids, gates, accumulates pred (post-barrier:
        // half-B waves are already issuing next expert's MFMAs)
        if (hh == 0 && lane < 32) {
            float bb = b2[e];
            #pragma unroll
            for (int tt = 0; tt < 2; ++tt) {
                float s = yacc[tt] + ybuf[e & 1][tg][tt][col] + bb;
                float yv = 1.f / (1.f + __expf(-s));
                float gt = gates[(size_t)(tw + tt * 32 + col) * NE + e];
                pred[tt] = fmaf(gt, yv, pred[tt]);
            }
        }
        p ^= 1;
    }

    if (hh == 0 && lane < 32) {
        pred_out[tw + col]      = pred[0];
        pred_out[tw + 32 + col] = pred[1];
    }
}

// ---------------------------------------------------------------------------
extern "C" void kernel_launch(void* const* d_in, const int* in_sizes, int n_in,
                              void* d_out, int out_size, void* d_ws, size_t ws_size,
                              hipStream_t stream) {
    (void)in_sizes; (void)n_in; (void)out_size; (void)ws_size;
    const float* x  = (const float*)d_in[0];
    const float* cp = (const float*)d_in[1];
    const float* W1 = (const float*)d_in[2];
    const float* b1 = (const float*)d_in[3];
    const float* W2 = (const float*)d_in[4];
    const float* b2 = (const float*)d_in[5];

    float* out   = (float*)d_out;
    float* pred  = out;                       // [131072]
    float* gates = out + 131072;              // [131072*8]
    float* used  = out + 1179648;             // [131072]
    float* inf   = out + 1310720;             // [8]
    float* cnt   = out + 1310728;             // [8]

    unsigned short* wfrag = (unsigned short*)d_ws;           // 512 KB frag W1
    float* pk   = (float*)((char*)d_ws + 524288);            // 16 KB b1/w2 table
    float* part = (float*)((char*)d_ws + 540672);            // 32 KB partials

    prep_w1<<<dim3(1025), dim3(256), 0, stream>>>(W1, b1, W2, wfrag, pk);
    gates_kernel<<<dim3(512), dim3(256), 0, stream>>>(cp, gates, used, part);
    reduce_kernel<<<dim3(1), dim3(64), 0, stream>>>(part, inf, cnt);
    moe_main<<<dim3(256), dim3(1024), 0, stream>>>(x, wfrag, pk, b2, gates, pred);
}

// Round 9
// 88.002 us; speedup vs baseline: 3.5260x; 1.2523x over previous
//
#include <hip/hip_runtime.h>
#include <math.h>

#define NE  8
#define HID 256

typedef __attribute__((ext_vector_type(8)))  short short8;
typedef __attribute__((ext_vector_type(16))) float f32x16;

static __device__ __forceinline__ unsigned short f2bf(float f) {
    unsigned int u = __float_as_uint(f);
    return (unsigned short)((u + 0x7FFFu + ((u >> 16) & 1u)) >> 16);
}

static __device__ __forceinline__ short8 pack8(float4 a, float4 b) {
    short8 r;
    r[0] = (short)f2bf(a.x); r[1] = (short)f2bf(a.y);
    r[2] = (short)f2bf(a.z); r[3] = (short)f2bf(a.w);
    r[4] = (short)f2bf(b.x); r[5] = (short)f2bf(b.y);
    r[6] = (short)f2bf(b.z); r[7] = (short)f2bf(b.w);
    return r;
}

// ---------------------------------------------------------------------------
// Kernel 1 (blocks 0..1023): W1 [E][128][256] -> bf16 frag-linear.
//   frag (e, hrt<8, kt<8): [lane][j] = W1[e][kt*16+(lane>>5)*8+j][hrt*32+(lane&31)]
// Block 1024: pk table [e][hrt][q][g][8] f32: j<4 -> b1[h], j>=4 -> W2[h].
// ---------------------------------------------------------------------------
__global__ void prep_w1(const float* __restrict__ W1, const float* __restrict__ b1,
                        const float* __restrict__ W2,
                        unsigned short* __restrict__ wfr, float* __restrict__ pk) {
    if (blockIdx.x < 1024) {
        int f = blockIdx.x * 256 + threadIdx.x;     // 262144 total
        int j   = f & 7;
        int l   = (f >> 3) & 63;
        int kt  = (f >> 9) & 7;
        int hrt = (f >> 12) & 7;
        int e   = f >> 15;
        int k = kt * 16 + ((l >> 5) * 8) + j;
        int h = hrt * 32 + (l & 31);
        wfr[f] = f2bf(W1[((size_t)e * 128 + k) * HID + h]);
    } else {
        for (int i = threadIdx.x; i < 4096; i += 256) {
            int j   = i & 7;
            int g   = (i >> 3) & 1;
            int q   = (i >> 4) & 3;
            int hrt = (i >> 6) & 7;
            int e   = i >> 9;
            int h = hrt * 32 + q * 8 + g * 4 + (j & 3);
            pk[i] = (j < 4) ? b1[e * HID + h] : W2[e * HID + h];
        }
    }
}

// ---------------------------------------------------------------------------
// Kernel 2: gating softmax (exact fp32) + experts_used + per-block partials
// ---------------------------------------------------------------------------
__global__ void gates_kernel(const float* __restrict__ cp,
                             float* __restrict__ gates_out,
                             float* __restrict__ used_out,
                             float* __restrict__ part) {
    __shared__ float wp_[4][16];
    int tid = threadIdx.x;
    int b = blockIdx.x * 256 + tid;

    float g[8];
    {
        const float4* c4 = (const float4*)(cp + (size_t)b * NE);
        float4 a0 = c4[0], a1 = c4[1];
        g[0]=a0.x; g[1]=a0.y; g[2]=a0.z; g[3]=a0.w;
        g[4]=a1.x; g[5]=a1.y; g[6]=a1.z; g[7]=a1.w;
    }
    float m = g[0];
    #pragma unroll
    for (int i = 1; i < 8; ++i) m = fmaxf(m, g[i]);
    float s = 0.f;
    #pragma unroll
    for (int i = 0; i < 8; ++i) { g[i] = __expf(g[i] - m); s += g[i]; }
    float inv = 1.f / s;
    #pragma unroll
    for (int i = 0; i < 8; ++i) g[i] *= inv;

    {
        float4 o0 = make_float4(g[0], g[1], g[2], g[3]);
        float4 o1 = make_float4(g[4], g[5], g[6], g[7]);
        float4* g4 = (float4*)(gates_out + (size_t)b * NE);
        g4[0] = o0; g4[1] = o1;
    }
    float v[16];
    float used = 0.f;
    #pragma unroll
    for (int i = 0; i < 8; ++i) {
        float a = (g[i] > 0.01f) ? 1.f : 0.f;
        used += a;
        v[i] = g[i];
        v[8 + i] = a;
    }
    used_out[b] = used;

    #pragma unroll
    for (int d = 32; d >= 1; d >>= 1)
        #pragma unroll
        for (int i = 0; i < 16; ++i)
            v[i] += __shfl_down(v[i], d, 64);
    int lane = tid & 63, wid = tid >> 6;
    if (lane == 0)
        #pragma unroll
        for (int i = 0; i < 16; ++i) wp_[wid][i] = v[i];
    __syncthreads();
    if (tid < 16)
        part[(size_t)blockIdx.x * 16 + tid] =
            wp_[0][tid] + wp_[1][tid] + wp_[2][tid] + wp_[3][tid];
}

// 512-thread deterministic reduce: 32 partial-threads per output, LDS tree.
__global__ void reduce_kernel(const float* __restrict__ part,
                              float* __restrict__ inf_out,
                              float* __restrict__ cnt_out) {
    __shared__ float red[16][32];
    int t = threadIdx.x;
    int o = t & 15, i = t >> 4;          // o: output slot, i: 0..31 chunk
    float s = 0.f;
    for (int k = i; k < 512; k += 32) s += part[(size_t)k * 16 + o];
    red[o][i] = s;
    __syncthreads();
    if (t < 16) {
        float r = 0.f;
        #pragma unroll
        for (int j = 0; j < 32; ++j) r += red[t][j];
        if (t < 8) inf_out[t] = r;
        else       cnt_out[t - 8] = r;
    }
}

// ---------------------------------------------------------------------------
// Kernel 4: main MoE. 256 blocks x 512 thr (8 waves = 2/SIMD). Wave = 64
// tokens x all 8 experts x all 256 h. W1 dbuf 2x64KB. SOFTWARE-PIPELINED:
// epilogue of hrt-1 is interleaved between the MFMAs of hrt (2 MFMA + ~8
// VALU per kt step) via named acc ping-pong (no dynamic idx -> no scratch).
// Per-expert tail is tiny; gates loads hoisted to expert start.
// launch_bounds(512,2): cap 256 total regs -- never force 128 (r5/7/8 spill).
// ---------------------------------------------------------------------------
#define MFMA_ __builtin_amdgcn_mfma_f32_32x32x16_bf16

// MFMAs of HRT into C0/C1 interleaved with epilogue of PH (acc P0/P1)
#define STEP(HRT, C0, C1, P0, P1, PH) { \
    float4 b1q, w2q; \
    _Pragma("unroll") \
    for (int kt = 0; kt < 8; ++kt) { \
        short8 w = *(const short8*)&W1s[p][(((HRT) * 8 + kt) * 64 + lane) * 8]; \
        C0 = MFMA_(w, xf[0][kt], C0, 0, 0, 0); \
        C1 = MFMA_(w, xf[1][kt], C1, 0, 0, 0); \
        int q = kt >> 1; \
        if ((kt & 1) == 0) { \
            int base = (((e * 8 + (PH)) * 4 + q) * 2 + g) * 8; \
            b1q = *(const float4*)&pks[base]; \
            w2q = *(const float4*)&pks[base + 4]; \
            ye0 = fmaf(fmaxf(P0[q * 4 + 0] + b1q.x, 0.f), w2q.x, ye0); \
            ye1 = fmaf(fmaxf(P1[q * 4 + 0] + b1q.x, 0.f), w2q.x, ye1); \
            ye0 = fmaf(fmaxf(P0[q * 4 + 1] + b1q.y, 0.f), w2q.y, ye0); \
            ye1 = fmaf(fmaxf(P1[q * 4 + 1] + b1q.y, 0.f), w2q.y, ye1); \
        } else { \
            ye0 = fmaf(fmaxf(P0[q * 4 + 2] + b1q.z, 0.f), w2q.z, ye0); \
            ye1 = fmaf(fmaxf(P1[q * 4 + 2] + b1q.z, 0.f), w2q.z, ye1); \
            ye0 = fmaf(fmaxf(P0[q * 4 + 3] + b1q.w, 0.f), w2q.w, ye0); \
            ye1 = fmaf(fmaxf(P1[q * 4 + 3] + b1q.w, 0.f), w2q.w, ye1); \
        } \
    } }

#define STEP_NOEPI(HRT, C0, C1) { \
    _Pragma("unroll") \
    for (int kt = 0; kt < 8; ++kt) { \
        short8 w = *(const short8*)&W1s[p][(((HRT) * 8 + kt) * 64 + lane) * 8]; \
        C0 = MFMA_(w, xf[0][kt], C0, 0, 0, 0); \
        C1 = MFMA_(w, xf[1][kt], C1, 0, 0, 0); \
    } }

#define EPI_TAIL(P0, P1, PH) { \
    _Pragma("unroll") \
    for (int q = 0; q < 4; ++q) { \
        int base = (((e * 8 + (PH)) * 4 + q) * 2 + g) * 8; \
        float4 b1q = *(const float4*)&pks[base]; \
        float4 w2q = *(const float4*)&pks[base + 4]; \
        ye0 = fmaf(fmaxf(P0[q * 4 + 0] + b1q.x, 0.f), w2q.x, ye0); \
        ye1 = fmaf(fmaxf(P1[q * 4 + 0] + b1q.x, 0.f), w2q.x, ye1); \
        ye0 = fmaf(fmaxf(P0[q * 4 + 1] + b1q.y, 0.f), w2q.y, ye0); \
        ye1 = fmaf(fmaxf(P1[q * 4 + 1] + b1q.y, 0.f), w2q.y, ye1); \
        ye0 = fmaf(fmaxf(P0[q * 4 + 2] + b1q.z, 0.f), w2q.z, ye0); \
        ye1 = fmaf(fmaxf(P1[q * 4 + 2] + b1q.z, 0.f), w2q.z, ye1); \
        ye0 = fmaf(fmaxf(P0[q * 4 + 3] + b1q.w, 0.f), w2q.w, ye0); \
        ye1 = fmaf(fmaxf(P1[q * 4 + 3] + b1q.w, 0.f), w2q.w, ye1); \
    } }

__global__ __launch_bounds__(512, 2)
void moe_main(const float* __restrict__ x,
              const unsigned short* __restrict__ wfr,
              const float* __restrict__ pk,
              const float* __restrict__ b2,
              const float* __restrict__ gates,
              float* __restrict__ pred_out) {
    __shared__ unsigned short W1s[2][8 * 8 * 64 * 8];   // 2 x 64 KB
    __shared__ float pks[4096];                         // 16 KB

    const int tid  = threadIdx.x;
    const int lane = tid & 63;
    const int wid  = tid >> 6;          // 0..7
    const int g    = lane >> 5;
    const int col  = lane & 31;
    const int tw   = blockIdx.x * 512 + wid * 64;   // wave token base

    // ---- stage expert 0 into buf 0 (64 KB = 8 waves x 8 x 1KB)
    {
        const char* src = (const char*)wfr + (size_t)wid * 8192 + lane * 16;
        char* dst = (char*)&W1s[0][0] + wid * 8192;
        #pragma unroll
        for (int i = 0; i < 8; ++i)
            __builtin_amdgcn_global_load_lds(
                (const __attribute__((address_space(1))) unsigned int*)(src + i * 1024),
                (__attribute__((address_space(3))) unsigned int*)(dst + i * 1024),
                16, 0, 0);
    }
    // ---- pk table -> LDS (1024 float4)
    ((float4*)pks)[tid]       = ((const float4*)pk)[tid];
    ((float4*)pks)[tid + 512] = ((const float4*)pk)[tid + 512];

    // ---- x fragments -> registers: frag (tt<2, kt<8): token=tw+tt*32+col,
    //      k = kt*16 + g*8 + j
    short8 xf[2][8];
    #pragma unroll
    for (int tt = 0; tt < 2; ++tt) {
        const float* xr = x + ((size_t)(tw + tt * 32 + col)) * 128 + g * 8;
        #pragma unroll
        for (int kt = 0; kt < 8; ++kt) {
            float4 a = *(const float4*)(xr + kt * 16);
            float4 b = *(const float4*)(xr + kt * 16 + 4);
            xf[tt][kt] = pack8(a, b);
        }
    }

    float pred0 = 0.f, pred1 = 0.f;
    int p = 0;
    __syncthreads();   // drains: stage(e0), pks, x loads

    for (int e = 0; e < NE; ++e) {
        if (e < 7) {   // stage next expert into other buffer (drained at barrier)
            const char* src = (const char*)wfr + (size_t)(e + 1) * 65536
                            + (size_t)wid * 8192 + lane * 16;
            char* dst = (char*)&W1s[p ^ 1][0] + wid * 8192;
            #pragma unroll
            for (int i = 0; i < 8; ++i)
                __builtin_amdgcn_global_load_lds(
                    (const __attribute__((address_space(1))) unsigned int*)(src + i * 1024),
                    (__attribute__((address_space(3))) unsigned int*)(dst + i * 1024),
                    16, 0, 0);
        }

        // hoist gate loads -- latency hides under the MFMA stream below
        float gt0 = gates[(size_t)(tw + col) * NE + e];
        float gt1 = gates[(size_t)(tw + 32 + col) * NE + e];
        float bb  = b2[e];

        float ye0 = 0.f, ye1 = 0.f;
        f32x16 a0, a1, c0, c1;

        a0 = (f32x16)0.0f; a1 = (f32x16)0.0f;
        STEP_NOEPI(0, a0, a1)
        c0 = (f32x16)0.0f; c1 = (f32x16)0.0f;
        STEP(1, c0, c1, a0, a1, 0)
        a0 = (f32x16)0.0f; a1 = (f32x16)0.0f;
        STEP(2, a0, a1, c0, c1, 1)
        c0 = (f32x16)0.0f; c1 = (f32x16)0.0f;
        STEP(3, c0, c1, a0, a1, 2)
        a0 = (f32x16)0.0f; a1 = (f32x16)0.0f;
        STEP(4, a0, a1, c0, c1, 3)
        c0 = (f32x16)0.0f; c1 = (f32x16)0.0f;
        STEP(5, c0, c1, a0, a1, 4)
        a0 = (f32x16)0.0f; a1 = (f32x16)0.0f;
        STEP(6, a0, a1, c0, c1, 5)
        c0 = (f32x16)0.0f; c1 = (f32x16)0.0f;
        STEP(7, c0, c1, a0, a1, 6)
        EPI_TAIL(c0, c1, 7)

        // fold halves, sigmoid, gate-weight
        {
            float s0 = ye0 + __shfl_xor(ye0, 32, 64) + bb;
            float s1 = ye1 + __shfl_xor(ye1, 32, 64) + bb;
            float yv0 = 1.f / (1.f + __expf(-s0));
            float yv1 = 1.f / (1.f + __expf(-s1));
            pred0 = fmaf(gt0, yv0, pred0);
            pred1 = fmaf(gt1, yv1, pred1);
        }

        __syncthreads();   // buf[p] reads done; stage(e+1) drained
        p ^= 1;
    }

    if (lane < 32) {
        pred_out[tw + col]      = pred0;
        pred_out[tw + 32 + col] = pred1;
    }
}

// ---------------------------------------------------------------------------
extern "C" void kernel_launch(void* const* d_in, const int* in_sizes, int n_in,
                              void* d_out, int out_size, void* d_ws, size_t ws_size,
                              hipStream_t stream) {
    (void)in_sizes; (void)n_in; (void)out_size; (void)ws_size;
    const float* x  = (const float*)d_in[0];
    const float* cp = (const float*)d_in[1];
    const float* W1 = (const float*)d_in[2];
    const float* b1 = (const float*)d_in[3];
    const float* W2 = (const float*)d_in[4];
    const float* b2 = (const float*)d_in[5];

    float* out   = (float*)d_out;
    float* pred  = out;                       // [131072]
    float* gates = out + 131072;              // [131072*8]
    float* used  = out + 1179648;             // [131072]
    float* inf   = out + 1310720;             // [8]
    float* cnt   = out + 1310728;             // [8]

    unsigned short* wfrag = (unsigned short*)d_ws;           // 512 KB frag W1
    float* pk   = (float*)((char*)d_ws + 524288);            // 16 KB b1/w2 table
    float* part = (float*)((char*)d_ws + 540672);            // 32 KB partials

    prep_w1<<<dim3(1025), dim3(256), 0, stream>>>(W1, b1, W2, wfrag, pk);
    gates_kernel<<<dim3(512), dim3(256), 0, stream>>>(cp, gates, used, part);
    reduce_kernel<<<dim3(1), dim3(512), 0, stream>>>(part, inf, cnt);
    moe_main<<<dim3(256), dim3(512), 0, stream>>>(x, wfrag, pk, b2, gates, pred);
}